// Round 1
// baseline (38627.167 us; speedup 1.0000x reference)
//
#include <hip/hip_runtime.h>
#include <cmath>

// Problem constants
constexpr int SEQ  = 2048;   // sequence length S
constexpr int EMB  = 512;    // embed dim E
constexpr int HID  = 256;    // per-direction hidden H
constexpr int GATE = 1024;   // 4*H
constexpr int NTAG = 32;     // tagset T
constexpr float FNEG = -10000.0f;

// ---------------------------------------------------------------------------
// Kernel 1: px[dir][s][j] = emb[t_eff(dir,s)] . w_ih_dir[j] + b_dir[j]
// Tiled fp32 GEMM, 64x64 tile, K-tile 64, 256 threads, 4x4 acc per thread.
// dir==1 uses the reversed sequence (backward LSTM consumes emb[S-1-s]).
// ---------------------------------------------------------------------------
__global__ __launch_bounds__(256) void px_gemm(
    const int* __restrict__ sent, const float* __restrict__ embed,
    const float* __restrict__ w_ih_f, const float* __restrict__ b_f,
    const float* __restrict__ w_ih_b, const float* __restrict__ b_b,
    float* __restrict__ px)
{
  const int dir = blockIdx.z;
  const int tm = blockIdx.x, tn = blockIdx.y;
  const float* __restrict__ w_ih = dir ? w_ih_b : w_ih_f;
  const float* __restrict__ bias = dir ? b_b : b_f;
  __shared__ float As[64][65];   // +1 pad -> 2-way max bank aliasing (free)
  __shared__ float Bs[64][65];
  __shared__ int sidx[64];
  const int tid = threadIdx.x;
  if (tid < 64) {
    const int s = tm * 64 + tid;
    const int tpos = dir ? (SEQ - 1 - s) : s;
    sidx[tid] = sent[tpos];
  }
  __syncthreads();
  float acc[4][4] = {};
  const int tr = tid >> 4, tc = tid & 15;
  for (int k0 = 0; k0 < EMB; k0 += 64) {
    #pragma unroll
    for (int i = 0; i < 4; ++i) {
      const int v = tid + i * 256;           // 1024 float4 slots: 64 rows x 16
      const int r = v >> 4, kv = v & 15;
      const float4 a4 = *reinterpret_cast<const float4*>(
          &embed[(size_t)sidx[r] * EMB + k0 + kv * 4]);
      As[r][kv*4+0] = a4.x; As[r][kv*4+1] = a4.y;
      As[r][kv*4+2] = a4.z; As[r][kv*4+3] = a4.w;
      const float4 b4 = *reinterpret_cast<const float4*>(
          &w_ih[(size_t)(tn * 64 + r) * EMB + k0 + kv * 4]);
      Bs[r][kv*4+0] = b4.x; Bs[r][kv*4+1] = b4.y;
      Bs[r][kv*4+2] = b4.z; Bs[r][kv*4+3] = b4.w;
    }
    __syncthreads();
    #pragma unroll
    for (int kk = 0; kk < 64; ++kk) {
      float a[4], b[4];
      #pragma unroll
      for (int i = 0; i < 4; ++i) a[i] = As[tr + 16 * i][kk];
      #pragma unroll
      for (int jj = 0; jj < 4; ++jj) b[jj] = Bs[tc + 16 * jj][kk];
      #pragma unroll
      for (int i = 0; i < 4; ++i)
        #pragma unroll
        for (int jj = 0; jj < 4; ++jj)
          acc[i][jj] = fmaf(a[i], b[jj], acc[i][jj]);
    }
    __syncthreads();
  }
  #pragma unroll
  for (int i = 0; i < 4; ++i) {
    const int srow = tm * 64 + tr + 16 * i;
    #pragma unroll
    for (int jj = 0; jj < 4; ++jj) {
      const int j = tn * 64 + tc + 16 * jj;   // tc fastest -> coalesced stores
      px[((size_t)dir * SEQ + srow) * GATE + j] = acc[i][jj] + bias[j];
    }
  }
}

// ---------------------------------------------------------------------------
// Kernel 2: LSTM recurrence, one 1024-thread block per direction (2 blocks).
// W_hh (1 MB/dir) lives in VGPRs: thread (m=tid>>2, q=tid&3) owns rows
// 4m..4m+3 restricted to K-slice [64q, 64q+64) -> 256 weight regs/thread.
// h replicated 4x in LDS (stride 260 -> the 4 q-slices hit distinct banks).
// Partial gate sums land in gsh[q][row]; 256 epilogue threads reduce 4
// partials/gate, apply nonlinearities, update c (register), write new h.
// ---------------------------------------------------------------------------
__global__ __launch_bounds__(1024) void lstm_kernel(
    const float* __restrict__ px, const float* __restrict__ w_hh_f,
    const float* __restrict__ w_hh_b, const float* __restrict__ h0,
    const float* __restrict__ c0, float* __restrict__ hs)
{
  const int dir = blockIdx.x;
  const int tid = threadIdx.x;
  const int m = tid >> 2;      // 0..255 -> gate rows 4m..4m+3
  const int q = tid & 3;       // K-slice [64q, 64q+64)
  const float* __restrict__ w_hh = dir ? w_hh_b : w_hh_f;

  float w[4][64];
  #pragma unroll
  for (int r = 0; r < 4; ++r) {
    const float* __restrict__ wr = &w_hh[(size_t)(4 * m + r) * HID + 64 * q];
    #pragma unroll
    for (int k = 0; k < 64; k += 4) {
      const float4 w4 = *reinterpret_cast<const float4*>(&wr[k]);
      w[r][k] = w4.x; w[r][k+1] = w4.y; w[r][k+2] = w4.z; w[r][k+3] = w4.w;
    }
  }

  __shared__ float hrep[4 * 260];   // 4 copies of h, stride 260 (bank spread)
  __shared__ float gsh[4 * 1040];   // partials: slice q at q*1040 + row
  float c = 0.0f;
  if (tid < HID) {
    const float hv = h0[dir * HID + tid];
    #pragma unroll
    for (int qq = 0; qq < 4; ++qq) hrep[qq * 260 + tid] = hv;
    c = c0[dir * HID + tid];
  }
  __syncthreads();

  const float* __restrict__ pxd = px + (size_t)dir * SEQ * GATE;
  float* __restrict__ hout = hs + (size_t)dir * SEQ * HID;

  float4 pcur = make_float4(0.f, 0.f, 0.f, 0.f);
  if (q == 0) pcur = *reinterpret_cast<const float4*>(&pxd[4 * m]);

  for (int t = 0; t < SEQ; ++t) {
    // software-pipelined px prefetch (hides L2/HBM latency behind FMA loop)
    float4 pnext = make_float4(0.f, 0.f, 0.f, 0.f);
    if (q == 0) {
      const int tn = (t + 1 < SEQ) ? (t + 1) : (SEQ - 1);
      pnext = *reinterpret_cast<const float4*>(&pxd[(size_t)tn * GATE + 4 * m]);
    }
    float s0 = pcur.x, s1 = pcur.y, s2 = pcur.z, s3 = pcur.w;
    #pragma unroll
    for (int k = 0; k < 64; k += 4) {
      const float4 h4 = *reinterpret_cast<const float4*>(&hrep[q * 260 + k]);
      s0 = fmaf(h4.x, w[0][k], s0); s0 = fmaf(h4.y, w[0][k+1], s0);
      s0 = fmaf(h4.z, w[0][k+2], s0); s0 = fmaf(h4.w, w[0][k+3], s0);
      s1 = fmaf(h4.x, w[1][k], s1); s1 = fmaf(h4.y, w[1][k+1], s1);
      s1 = fmaf(h4.z, w[1][k+2], s1); s1 = fmaf(h4.w, w[1][k+3], s1);
      s2 = fmaf(h4.x, w[2][k], s2); s2 = fmaf(h4.y, w[2][k+1], s2);
      s2 = fmaf(h4.z, w[2][k+2], s2); s2 = fmaf(h4.w, w[2][k+3], s2);
      s3 = fmaf(h4.x, w[3][k], s3); s3 = fmaf(h4.y, w[3][k+1], s3);
      s3 = fmaf(h4.z, w[3][k+2], s3); s3 = fmaf(h4.w, w[3][k+3], s3);
    }
    *reinterpret_cast<float4*>(&gsh[q * 1040 + 4 * m]) =
        make_float4(s0, s1, s2, s3);
    __syncthreads();
    if (tid < HID) {
      const int r = tid;
      float ig = gsh[r]            + gsh[1040 + r]
               + gsh[2080 + r]     + gsh[3120 + r];
      float fg = gsh[HID + r]      + gsh[1040 + HID + r]
               + gsh[2080 + HID + r] + gsh[3120 + HID + r];
      float gg = gsh[2*HID + r]    + gsh[1040 + 2*HID + r]
               + gsh[2080 + 2*HID + r] + gsh[3120 + 2*HID + r];
      float og = gsh[3*HID + r]    + gsh[1040 + 3*HID + r]
               + gsh[2080 + 3*HID + r] + gsh[3120 + 3*HID + r];
      const float si = 1.0f / (1.0f + expf(-ig));
      const float sf = 1.0f / (1.0f + expf(-fg));
      const float so = 1.0f / (1.0f + expf(-og));
      const float cn = sf * c + si * tanhf(gg);
      c = cn;
      const float hn = so * tanhf(cn);
      #pragma unroll
      for (int qq = 0; qq < 4; ++qq) hrep[qq * 260 + r] = hn;
      hout[(size_t)t * HID + r] = hn;
    }
    __syncthreads();
    pcur = pnext;
  }
}

// ---------------------------------------------------------------------------
// Kernel 3: feats[t][j] = concat(h_fwd[t], h_bwd[S-1-t]) . w_tag[j] + b_tag[j]
// One block per t; 8 lanes per tag j, shfl-reduce within groups of 8.
// ---------------------------------------------------------------------------
__global__ __launch_bounds__(256) void feats_kernel(
    const float* __restrict__ hs, const float* __restrict__ w_tag,
    const float* __restrict__ b_tag, float* __restrict__ feats)
{
  const int t = blockIdx.x;
  const int tid = threadIdx.x;
  const int j = tid >> 3, p = tid & 7;
  const float* __restrict__ src = (p < 4)
      ? (hs + (size_t)t * HID + p * 64)                              // fwd half
      : (hs + (size_t)(SEQ + (SEQ - 1 - t)) * HID + (p - 4) * 64);   // bwd half
  const float* __restrict__ wt = w_tag + (size_t)j * (2 * HID) + p * 64;
  float sum = 0.f;
  #pragma unroll
  for (int k = 0; k < 64; k += 4) {
    const float4 x4 = *reinterpret_cast<const float4*>(&src[k]);
    const float4 w4 = *reinterpret_cast<const float4*>(&wt[k]);
    sum = fmaf(x4.x, w4.x, sum); sum = fmaf(x4.y, w4.y, sum);
    sum = fmaf(x4.z, w4.z, sum); sum = fmaf(x4.w, w4.w, sum);
  }
  sum += __shfl_down(sum, 4, 8);
  sum += __shfl_down(sum, 2, 8);
  sum += __shfl_down(sum, 1, 8);
  if (p == 0) feats[(size_t)t * NTAG + j] = sum + b_tag[j];
}

// ---------------------------------------------------------------------------
// Kernel 4: Viterbi + backtrace, single wave (64 threads = 1 wave, no
// barriers needed). Lane (j = lane&31, half = lane>>5) scans 16 prev-tags;
// halves merged via shfl. Backpointers in 64 KB LDS; lane 0 backtraces.
// Tie-breaking matches jnp.argmax (first index): strict '>' updates only,
// lower half preferred on ties.
// ---------------------------------------------------------------------------
__global__ __launch_bounds__(64) void viterbi_kernel(
    const float* __restrict__ feats, const float* __restrict__ trans,
    float* __restrict__ out)
{
  __shared__ unsigned char bp[SEQ][NTAG];   // 64 KiB exactly
  const int lane = threadIdx.x;
  const int j = lane & 31, half = lane >> 5;
  float tr[16];
  #pragma unroll
  for (int qq = 0; qq < 16; ++qq) tr[qq] = trans[j * NTAG + half * 16 + qq];
  float fv = (j == 30) ? 0.0f : FNEG;       // START = 30
  float fcur = feats[j];
  for (int t = 0; t < SEQ; ++t) {
    const int tn = (t + 1 < SEQ) ? (t + 1) : (SEQ - 1);
    const float fnext = feats[(size_t)tn * NTAG + j];
    float best = -3.0e38f; int barg = 0;
    #pragma unroll
    for (int qq = 0; qq < 16; ++qq) {
      const int p = half * 16 + qq;
      const float sc = __shfl(fv, p) + tr[qq];
      if (sc > best) { best = sc; barg = p; }
    }
    const float ob = __shfl_down(best, 32);
    const int   oa = __shfl_down(barg, 32);
    float fvnew = 0.f;
    if (half == 0) {
      if (ob > best) { best = ob; barg = oa; }
      bp[t][j] = (unsigned char)barg;
      fvnew = best + fcur;
    }
    fv = __shfl(fvnew, j);   // broadcast updated fv[j] to both halves
    fcur = fnext;
  }
  float term = fv + trans[31 * NTAG + j];   // STOP = 31
  int idx = j;
  #pragma unroll
  for (int off = 16; off >= 1; off >>= 1) {
    const float ov = __shfl_down(term, off, 32);
    const int   oi = __shfl_down(idx, off, 32);
    if (ov > term) { term = ov; idx = oi; }
  }
  if (lane == 0) {
    out[0] = term;                 // path score
    int tag = idx;
    for (int t = SEQ - 1; t >= 0; --t) {
      out[1 + t] = (float)tag;     // y[S-1] = best_last; y[t] = bp[t+1][y[t+1]]
      tag = bp[t][tag];
    }
  }
}

// ---------------------------------------------------------------------------
extern "C" void kernel_launch(void* const* d_in, const int* in_sizes, int n_in,
                              void* d_out, int out_size, void* d_ws, size_t ws_size,
                              hipStream_t stream)
{
  (void)in_sizes; (void)n_in; (void)out_size; (void)ws_size;
  const int*   sent   = (const int*)  d_in[0];
  const float* embed  = (const float*)d_in[1];
  const float* w_ih_f = (const float*)d_in[2];
  const float* w_hh_f = (const float*)d_in[3];
  const float* b_f    = (const float*)d_in[4];
  const float* w_ih_b = (const float*)d_in[5];
  const float* w_hh_b = (const float*)d_in[6];
  const float* b_b    = (const float*)d_in[7];
  const float* w_tag  = (const float*)d_in[8];
  const float* b_tag  = (const float*)d_in[9];
  const float* trans  = (const float*)d_in[10];
  const float* h0     = (const float*)d_in[11];
  const float* c0     = (const float*)d_in[12];
  float* out = (float*)d_out;

  // workspace layout (floats): px[2][S][1024] | hs[2][S][256] | feats[S][32]
  float* px    = (float*)d_ws;
  float* hsbuf = px + (size_t)2 * SEQ * GATE;
  float* feats = hsbuf + (size_t)2 * SEQ * HID;

  dim3 gemm_grid(SEQ / 64, GATE / 64, 2);
  px_gemm<<<gemm_grid, 256, 0, stream>>>(sent, embed, w_ih_f, b_f,
                                         w_ih_b, b_b, px);
  lstm_kernel<<<2, 1024, 0, stream>>>(px, w_hh_f, w_hh_b, h0, c0, hsbuf);
  feats_kernel<<<SEQ, 256, 0, stream>>>(hsbuf, w_tag, b_tag, feats);
  viterbi_kernel<<<1, 64, 0, stream>>>(feats, trans, out);
}

// Round 2
// 7617.118 us; speedup vs baseline: 5.0711x; 5.0711x over previous
//
#include <hip/hip_runtime.h>
#include <cstdint>
#include <cmath>

// Problem constants
constexpr int SEQ  = 2048;   // sequence length S
constexpr int EMB  = 512;    // embed dim E
constexpr int HID  = 256;    // per-direction hidden H
constexpr int GATE = 1024;   // 4*H
constexpr int NTAG = 32;     // tagset T
constexpr float FNEG = -10000.0f;
constexpr int DBLK = 8;      // blocks per direction for the LSTM

// ---------------------------------------------------------------------------
// Kernel 1: px[dir][s][j] = emb[t_eff(dir,s)] . w_ih_dir[j] + b_dir[j]
// Tiled fp32 GEMM, 64x64 tile, K-tile 64, 256 threads, 4x4 acc per thread.
// dir==1 uses the reversed sequence (backward LSTM consumes emb[S-1-s]).
// ---------------------------------------------------------------------------
__global__ __launch_bounds__(256) void px_gemm(
    const int* __restrict__ sent, const float* __restrict__ embed,
    const float* __restrict__ w_ih_f, const float* __restrict__ b_f,
    const float* __restrict__ w_ih_b, const float* __restrict__ b_b,
    float* __restrict__ px)
{
  const int dir = blockIdx.z;
  const int tm = blockIdx.x, tn = blockIdx.y;
  const float* __restrict__ w_ih = dir ? w_ih_b : w_ih_f;
  const float* __restrict__ bias = dir ? b_b : b_f;
  __shared__ float As[64][65];   // +1 pad -> 2-way max bank aliasing (free)
  __shared__ float Bs[64][65];
  __shared__ int sidx[64];
  const int tid = threadIdx.x;
  if (tid < 64) {
    const int s = tm * 64 + tid;
    const int tpos = dir ? (SEQ - 1 - s) : s;
    sidx[tid] = sent[tpos];
  }
  __syncthreads();
  float acc[4][4] = {};
  const int tr = tid >> 4, tc = tid & 15;
  for (int k0 = 0; k0 < EMB; k0 += 64) {
    #pragma unroll
    for (int i = 0; i < 4; ++i) {
      const int v = tid + i * 256;           // 1024 float4 slots: 64 rows x 16
      const int r = v >> 4, kv = v & 15;
      const float4 a4 = *reinterpret_cast<const float4*>(
          &embed[(size_t)sidx[r] * EMB + k0 + kv * 4]);
      As[r][kv*4+0] = a4.x; As[r][kv*4+1] = a4.y;
      As[r][kv*4+2] = a4.z; As[r][kv*4+3] = a4.w;
      const float4 b4 = *reinterpret_cast<const float4*>(
          &w_ih[(size_t)(tn * 64 + r) * EMB + k0 + kv * 4]);
      Bs[r][kv*4+0] = b4.x; Bs[r][kv*4+1] = b4.y;
      Bs[r][kv*4+2] = b4.z; Bs[r][kv*4+3] = b4.w;
    }
    __syncthreads();
    #pragma unroll
    for (int kk = 0; kk < 64; ++kk) {
      float a[4], b[4];
      #pragma unroll
      for (int i = 0; i < 4; ++i) a[i] = As[tr + 16 * i][kk];
      #pragma unroll
      for (int jj = 0; jj < 4; ++jj) b[jj] = Bs[tc + 16 * jj][kk];
      #pragma unroll
      for (int i = 0; i < 4; ++i)
        #pragma unroll
        for (int jj = 0; jj < 4; ++jj)
          acc[i][jj] = fmaf(a[i], b[jj], acc[i][jj]);
    }
    __syncthreads();
  }
  #pragma unroll
  for (int i = 0; i < 4; ++i) {
    const int srow = tm * 64 + tr + 16 * i;
    #pragma unroll
    for (int jj = 0; jj < 4; ++jj) {
      const int j = tn * 64 + tc + 16 * jj;   // tc fastest -> coalesced stores
      px[((size_t)dir * SEQ + srow) * GATE + j] = acc[i][jj] + bias[j];
    }
  }
}

// ---------------------------------------------------------------------------
// Kernel 2: LSTM recurrence distributed over 2 x DBLK blocks (one CU each).
// Why: W_hh is 1 MB/direction but a CU register file is only ~512 KB and a
// 1024-thread block caps the allocator at 128 VGPR/thread (R1 spilled, 37 ms).
// Each block (256 threads, 1 wave/SIMD, <=512 VGPR budget) owns 32 hidden
// units = 128 gate rows = 128 floats/thread, held in 32 float4 registers.
// Thread (j = tid>>3, q = tid&7): unit j, K-slice [32q,32q+32); the 4 gate
// rows of unit j live in ONE thread -> shfl-reduce over the 8 adjacent q
// lanes, and cell state c stays in thread (j,0)'s register.
// Cross-block h broadcast: self-tagged 8B packets (epoch=t+1 | h bits) via
// agent-scope atomics (sc1 -> LLC-coherent across XCDs; per-XCD L2s are NOT
// cross-coherent). 0xAA poison / zeros never alias an epoch -> no flags, no
// memset, safe under graph replay.
// h in LDS is stored with a +4 pad per 32-float chunk (chunk q at 36q) so the
// 8 q-slices hit disjoint bank groups (conflict-free b128 reads).
// ---------------------------------------------------------------------------
__global__ __launch_bounds__(256, 1) void lstm_sync(
    const float* __restrict__ px, const float* __restrict__ w_hh_f,
    const float* __restrict__ w_hh_b, const float* __restrict__ h0,
    const float* __restrict__ c0, float* __restrict__ hs,
    unsigned long long* __restrict__ hx)
{
  const int blk = blockIdx.x;
  const int dir = blk >> 3, b = blk & 7;
  const int tid = threadIdx.x;
  const int j = tid >> 3;          // unit within block's 32
  const int q = tid & 7;           // K-slice index (32 floats each)
  const int u = 32 * b + j;        // global hidden unit
  const float* __restrict__ w_hh = dir ? w_hh_b : w_hh_f;

  // Weight fragments: rows u, 256+u, 512+u, 768+u; cols [32q, 32q+32)
  float4 wi[8], wf[8], wg[8], wo[8];
  {
    const float* __restrict__ r0 = &w_hh[(size_t)u * HID + 32 * q];
    const float* __restrict__ r1 = r0 + (size_t)256 * HID;
    const float* __restrict__ r2 = r0 + (size_t)512 * HID;
    const float* __restrict__ r3 = r0 + (size_t)768 * HID;
    #pragma unroll
    for (int m = 0; m < 8; ++m) {
      wi[m] = *reinterpret_cast<const float4*>(&r0[4 * m]);
      wf[m] = *reinterpret_cast<const float4*>(&r1[4 * m]);
      wg[m] = *reinterpret_cast<const float4*>(&r2[4 * m]);
      wo[m] = *reinterpret_cast<const float4*>(&r3[4 * m]);
    }
  }

  __shared__ float hsh[8 * 36];    // h, chunk q at 36q (bank-spread pad)
  float c = 0.0f;
  if (tid < HID) hsh[36 * (tid >> 5) + (tid & 31)] = h0[dir * HID + tid];
  if (q == 0) c = c0[dir * HID + u];
  __syncthreads();

  const size_t pxbase = (size_t)dir * SEQ * GATE;
  float pi = 0.f, pf = 0.f, pg = 0.f, po = 0.f;
  if (q == 0) {
    pi = px[pxbase + u];        pf = px[pxbase + 256 + u];
    pg = px[pxbase + 512 + u];  po = px[pxbase + 768 + u];
  }

  for (int t = 0; t < SEQ; ++t) {
    // prefetch next step's px behind the FMA phase
    float ni = 0.f, nf = 0.f, ng = 0.f, no = 0.f;
    if (q == 0 && t + 1 < SEQ) {
      const size_t nb = pxbase + (size_t)(t + 1) * GATE;
      ni = px[nb + u];        nf = px[nb + 256 + u];
      ng = px[nb + 512 + u];  no = px[nb + 768 + u];
    }

    float si = 0.f, sf = 0.f, sg = 0.f, so = 0.f;
    #pragma unroll
    for (int m = 0; m < 8; ++m) {
      const float4 h4 = *reinterpret_cast<const float4*>(&hsh[36 * q + 4 * m]);
      si = fmaf(h4.x, wi[m].x, si); si = fmaf(h4.y, wi[m].y, si);
      si = fmaf(h4.z, wi[m].z, si); si = fmaf(h4.w, wi[m].w, si);
      sf = fmaf(h4.x, wf[m].x, sf); sf = fmaf(h4.y, wf[m].y, sf);
      sf = fmaf(h4.z, wf[m].z, sf); sf = fmaf(h4.w, wf[m].w, sf);
      sg = fmaf(h4.x, wg[m].x, sg); sg = fmaf(h4.y, wg[m].y, sg);
      sg = fmaf(h4.z, wg[m].z, sg); sg = fmaf(h4.w, wg[m].w, sg);
      so = fmaf(h4.x, wo[m].x, so); so = fmaf(h4.y, wo[m].y, so);
      so = fmaf(h4.z, wo[m].z, so); so = fmaf(h4.w, wo[m].w, so);
    }
    // reduce the 8 K-slice partials (adjacent lanes) into q==0
    #pragma unroll
    for (int off = 4; off >= 1; off >>= 1) {
      si += __shfl_down(si, off, 8);
      sf += __shfl_down(sf, off, 8);
      sg += __shfl_down(sg, off, 8);
      so += __shfl_down(so, off, 8);
    }

    if (q == 0) {
      const float gi = si + pi, gf = sf + pf, gg = sg + pg, go = so + po;
      const float ai = 1.0f / (1.0f + expf(-gi));
      const float af = 1.0f / (1.0f + expf(-gf));
      const float ao = 1.0f / (1.0f + expf(-go));
      c = af * c + ai * tanhf(gg);
      const float hn = ao * tanhf(c);
      // publish first (critical path), then the plain copy for later kernels
      const unsigned long long pk =
          ((unsigned long long)(unsigned)(t + 1) << 32) |
          (unsigned long long)__float_as_uint(hn);
      __hip_atomic_store(&hx[((size_t)dir * SEQ + t) * HID + u], pk,
                         __ATOMIC_RELAXED, __HIP_MEMORY_SCOPE_AGENT);
      hs[((size_t)dir * SEQ + t) * HID + u] = hn;
    }
    pi = ni; pf = nf; pg = ng; po = no;
    if (t == SEQ - 1) break;     // uniform: no one consumes the last broadcast

    // gather the full h_t (256 tagged packets) from LLC
    const size_t gidx = ((size_t)dir * SEQ + t) * HID + tid;
    const unsigned want = (unsigned)(t + 1);
    bool ok = false; float hv = 0.f;
    do {
      if (!ok) {
        const unsigned long long v = __hip_atomic_load(
            &hx[gidx], __ATOMIC_RELAXED, __HIP_MEMORY_SCOPE_AGENT);
        if ((unsigned)(v >> 32) == want) {
          hv = __uint_as_float((unsigned)v);
          ok = true;
        } else {
          __builtin_amdgcn_s_sleep(1);
        }
      }
    } while (__syncthreads_count((int)ok) < 256);
    // barrier above also orders: all compute reads of hsh are done
    hsh[36 * (tid >> 5) + (tid & 31)] = hv;
    __syncthreads();
  }
}

// ---------------------------------------------------------------------------
// Kernel 3: feats[t][j] = concat(h_fwd[t], h_bwd[S-1-t]) . w_tag[j] + b_tag[j]
// One block per t; 8 lanes per tag j, shfl-reduce within groups of 8.
// ---------------------------------------------------------------------------
__global__ __launch_bounds__(256) void feats_kernel(
    const float* __restrict__ hs, const float* __restrict__ w_tag,
    const float* __restrict__ b_tag, float* __restrict__ feats)
{
  const int t = blockIdx.x;
  const int tid = threadIdx.x;
  const int j = tid >> 3, p = tid & 7;
  const float* __restrict__ src = (p < 4)
      ? (hs + (size_t)t * HID + p * 64)                              // fwd half
      : (hs + (size_t)(SEQ + (SEQ - 1 - t)) * HID + (p - 4) * 64);   // bwd half
  const float* __restrict__ wt = w_tag + (size_t)j * (2 * HID) + p * 64;
  float sum = 0.f;
  #pragma unroll
  for (int k = 0; k < 64; k += 4) {
    const float4 x4 = *reinterpret_cast<const float4*>(&src[k]);
    const float4 w4 = *reinterpret_cast<const float4*>(&wt[k]);
    sum = fmaf(x4.x, w4.x, sum); sum = fmaf(x4.y, w4.y, sum);
    sum = fmaf(x4.z, w4.z, sum); sum = fmaf(x4.w, w4.w, sum);
  }
  sum += __shfl_down(sum, 4, 8);
  sum += __shfl_down(sum, 2, 8);
  sum += __shfl_down(sum, 1, 8);
  if (p == 0) feats[(size_t)t * NTAG + j] = sum + b_tag[j];
}

// ---------------------------------------------------------------------------
// Kernel 4: Viterbi + backtrace, single wave (64 threads = 1 wave, no
// barriers needed). Lane (j = lane&31, half = lane>>5) scans 16 prev-tags;
// halves merged via shfl. Backpointers in 64 KB LDS; lane 0 backtraces.
// Tie-breaking matches jnp.argmax (first index): strict '>' updates only,
// lower half preferred on ties.
// ---------------------------------------------------------------------------
__global__ __launch_bounds__(64) void viterbi_kernel(
    const float* __restrict__ feats, const float* __restrict__ trans,
    float* __restrict__ out)
{
  __shared__ unsigned char bp[SEQ][NTAG];   // 64 KiB exactly
  const int lane = threadIdx.x;
  const int j = lane & 31, half = lane >> 5;
  float tr[16];
  #pragma unroll
  for (int qq = 0; qq < 16; ++qq) tr[qq] = trans[j * NTAG + half * 16 + qq];
  float fv = (j == 30) ? 0.0f : FNEG;       // START = 30
  float fcur = feats[j];
  for (int t = 0; t < SEQ; ++t) {
    const int tn = (t + 1 < SEQ) ? (t + 1) : (SEQ - 1);
    const float fnext = feats[(size_t)tn * NTAG + j];
    float best = -3.0e38f; int barg = 0;
    #pragma unroll
    for (int qq = 0; qq < 16; ++qq) {
      const int p = half * 16 + qq;
      const float sc = __shfl(fv, p) + tr[qq];
      if (sc > best) { best = sc; barg = p; }
    }
    const float ob = __shfl_down(best, 32);
    const int   oa = __shfl_down(barg, 32);
    float fvnew = 0.f;
    if (half == 0) {
      if (ob > best) { best = ob; barg = oa; }
      bp[t][j] = (unsigned char)barg;
      fvnew = best + fcur;
    }
    fv = __shfl(fvnew, j);   // broadcast updated fv[j] to both halves
    fcur = fnext;
  }
  float term = fv + trans[31 * NTAG + j];   // STOP = 31
  int idx = j;
  #pragma unroll
  for (int off = 16; off >= 1; off >>= 1) {
    const float ov = __shfl_down(term, off, 32);
    const int   oi = __shfl_down(idx, off, 32);
    if (ov > term) { term = ov; idx = oi; }
  }
  if (lane == 0) {
    out[0] = term;                 // path score
    int tag = idx;
    for (int t = SEQ - 1; t >= 0; --t) {
      out[1 + t] = (float)tag;     // y[S-1] = best_last; y[t] = bp[t+1][y[t+1]]
      tag = bp[t][tag];
    }
  }
}

// ---------------------------------------------------------------------------
extern "C" void kernel_launch(void* const* d_in, const int* in_sizes, int n_in,
                              void* d_out, int out_size, void* d_ws, size_t ws_size,
                              hipStream_t stream)
{
  (void)in_sizes; (void)n_in; (void)out_size; (void)ws_size;
  const int*   sent   = (const int*)  d_in[0];
  const float* embed  = (const float*)d_in[1];
  const float* w_ih_f = (const float*)d_in[2];
  const float* w_hh_f = (const float*)d_in[3];
  const float* b_f    = (const float*)d_in[4];
  const float* w_ih_b = (const float*)d_in[5];
  const float* w_hh_b = (const float*)d_in[6];
  const float* b_b    = (const float*)d_in[7];
  const float* w_tag  = (const float*)d_in[8];
  const float* b_tag  = (const float*)d_in[9];
  const float* trans  = (const float*)d_in[10];
  const float* h0     = (const float*)d_in[11];
  const float* c0     = (const float*)d_in[12];
  float* out = (float*)d_out;

  // workspace (d_ws): hx[2][S][256] u64 | px[2][S][1024] | hs[2][S][256] | feats[S][32]
  unsigned long long* hx = (unsigned long long*)d_ws;          // 8 MB, 8B-aligned
  float* px    = (float*)(hx + (size_t)2 * SEQ * HID);         // 16 MB
  float* hsbuf = px + (size_t)2 * SEQ * GATE;                  // 4 MB
  float* feats = hsbuf + (size_t)2 * SEQ * HID;                // 256 KB

  dim3 gemm_grid(SEQ / 64, GATE / 64, 2);
  px_gemm<<<gemm_grid, 256, 0, stream>>>(sent, embed, w_ih_f, b_f,
                                         w_ih_b, b_b, px);
  lstm_sync<<<2 * DBLK, 256, 0, stream>>>(px, w_hh_f, w_hh_b, h0, c0,
                                          hsbuf, hx);
  feats_kernel<<<SEQ, 256, 0, stream>>>(hsbuf, w_tag, b_tag, feats);
  viterbi_kernel<<<1, 64, 0, stream>>>(feats, trans, out);
}

// Round 3
// 6214.911 us; speedup vs baseline: 6.2152x; 1.2256x over previous
//
#include <hip/hip_runtime.h>
#include <cstdint>
#include <cmath>

// Problem constants
constexpr int SEQ  = 2048;   // sequence length S
constexpr int EMB  = 512;    // embed dim E
constexpr int HID  = 256;    // per-direction hidden H
constexpr int GATE = 1024;   // 4*H
constexpr int NTAG = 32;     // tagset T
constexpr float FNEG = -10000.0f;
constexpr int DBLK = 8;      // blocks per direction for the LSTM

// ---------------------------------------------------------------------------
// Kernel 1: px[dir][s][j] = emb[t_eff(dir,s)] . w_ih_dir[j] + b_dir[j]
// Tiled fp32 GEMM, 64x64 tile, K-tile 64, 256 threads, 4x4 acc per thread.
// dir==1 uses the reversed sequence (backward LSTM consumes emb[S-1-s]).
// ---------------------------------------------------------------------------
__global__ __launch_bounds__(256) void px_gemm(
    const int* __restrict__ sent, const float* __restrict__ embed,
    const float* __restrict__ w_ih_f, const float* __restrict__ b_f,
    const float* __restrict__ w_ih_b, const float* __restrict__ b_b,
    float* __restrict__ px)
{
  const int dir = blockIdx.z;
  const int tm = blockIdx.x, tn = blockIdx.y;
  const float* __restrict__ w_ih = dir ? w_ih_b : w_ih_f;
  const float* __restrict__ bias = dir ? b_b : b_f;
  __shared__ float As[64][65];   // +1 pad -> 2-way max bank aliasing (free)
  __shared__ float Bs[64][65];
  __shared__ int sidx[64];
  const int tid = threadIdx.x;
  if (tid < 64) {
    const int s = tm * 64 + tid;
    const int tpos = dir ? (SEQ - 1 - s) : s;
    sidx[tid] = sent[tpos];
  }
  __syncthreads();
  float acc[4][4] = {};
  const int tr = tid >> 4, tc = tid & 15;
  for (int k0 = 0; k0 < EMB; k0 += 64) {
    #pragma unroll
    for (int i = 0; i < 4; ++i) {
      const int v = tid + i * 256;           // 1024 float4 slots: 64 rows x 16
      const int r = v >> 4, kv = v & 15;
      const float4 a4 = *reinterpret_cast<const float4*>(
          &embed[(size_t)sidx[r] * EMB + k0 + kv * 4]);
      As[r][kv*4+0] = a4.x; As[r][kv*4+1] = a4.y;
      As[r][kv*4+2] = a4.z; As[r][kv*4+3] = a4.w;
      const float4 b4 = *reinterpret_cast<const float4*>(
          &w_ih[(size_t)(tn * 64 + r) * EMB + k0 + kv * 4]);
      Bs[r][kv*4+0] = b4.x; Bs[r][kv*4+1] = b4.y;
      Bs[r][kv*4+2] = b4.z; Bs[r][kv*4+3] = b4.w;
    }
    __syncthreads();
    #pragma unroll
    for (int kk = 0; kk < 64; ++kk) {
      float a[4], b[4];
      #pragma unroll
      for (int i = 0; i < 4; ++i) a[i] = As[tr + 16 * i][kk];
      #pragma unroll
      for (int jj = 0; jj < 4; ++jj) b[jj] = Bs[tc + 16 * jj][kk];
      #pragma unroll
      for (int i = 0; i < 4; ++i)
        #pragma unroll
        for (int jj = 0; jj < 4; ++jj)
          acc[i][jj] = fmaf(a[i], b[jj], acc[i][jj]);
    }
    __syncthreads();
  }
  #pragma unroll
  for (int i = 0; i < 4; ++i) {
    const int srow = tm * 64 + tr + 16 * i;
    #pragma unroll
    for (int jj = 0; jj < 4; ++jj) {
      const int j = tn * 64 + tc + 16 * jj;   // tc fastest -> coalesced stores
      px[((size_t)dir * SEQ + srow) * GATE + j] = acc[i][jj] + bias[j];
    }
  }
}

// ---------------------------------------------------------------------------
// Kernel 2: LSTM recurrence, 2 x DBLK blocks of 256 threads (one CU each).
// R2 lesson: __launch_bounds__(256,1) only sets MIN waves/EU; the backend
// still targeted ~5 waves/SIMD (VGPR_Count=88) and sank the 128 weight loads
// into the t-loop (FETCH_SIZE 58 MB of L2-miss residue). Fix: force
// amdgpu_waves_per_eu(1,1) -> 512-VGPR budget, weights stay resident.
// Layout: thread (j = tid>>3, q = tid&7) owns unit u=32b+j, K-slice
// [32q,32q+32): 4 gate rows x 32 cols = 32 float4 registers. Gate partials
// shfl-reduce over the 8 adjacent lanes; cell state c lives in lane q==0.
// Cross-block h broadcast: self-tagged 8B packets (epoch=t+1 | h bits) via
// agent-scope atomics (LLC-coherent; per-XCD L2s are NOT cross-coherent).
// Poison 0xAA never aliases an epoch -> no flags, no memset, graph-safe.
// Per-wave ballot polling (no per-iteration block barrier); own block's 32
// units go straight to LDS; h double-buffered on t-parity -> ONE
// __syncthreads per step.
// ---------------------------------------------------------------------------
__global__ __attribute__((amdgpu_flat_work_group_size(256, 256),
                          amdgpu_waves_per_eu(1, 1)))
void lstm_sync(
    const float* __restrict__ px, const float* __restrict__ w_hh_f,
    const float* __restrict__ w_hh_b, const float* __restrict__ h0,
    const float* __restrict__ c0, float* __restrict__ hs,
    unsigned long long* __restrict__ hx)
{
  const int blk = blockIdx.x;
  const int dir = blk >> 3, b = blk & 7;
  const int tid = threadIdx.x;
  const int j = tid >> 3;          // unit within block's 32
  const int q = tid & 7;           // K-slice index (32 floats each)
  const int u = 32 * b + j;        // global hidden unit
  const float* __restrict__ w_hh = dir ? w_hh_b : w_hh_f;

  // Weight fragments: rows u, 256+u, 512+u, 768+u; cols [32q, 32q+32)
  float4 wi[8], wf[8], wg[8], wo[8];
  {
    const float* __restrict__ r0 = &w_hh[(size_t)u * HID + 32 * q];
    const float* __restrict__ r1 = r0 + (size_t)256 * HID;
    const float* __restrict__ r2 = r0 + (size_t)512 * HID;
    const float* __restrict__ r3 = r0 + (size_t)768 * HID;
    #pragma unroll
    for (int m = 0; m < 8; ++m) {
      wi[m] = *reinterpret_cast<const float4*>(&r0[4 * m]);
      wf[m] = *reinterpret_cast<const float4*>(&r1[4 * m]);
      wg[m] = *reinterpret_cast<const float4*>(&r2[4 * m]);
      wo[m] = *reinterpret_cast<const float4*>(&r3[4 * m]);
    }
  }

  // h double-buffered; chunk q at 36q (bank-spread pad, conflict-free b128)
  __shared__ float hsh[2][8 * 36];
  float c = 0.0f;
  hsh[0][36 * (tid >> 5) + (tid & 31)] = h0[dir * HID + tid];
  if (q == 0) c = c0[dir * HID + u];
  __syncthreads();

  const size_t pxbase = (size_t)dir * SEQ * GATE;
  float pi = 0.f, pf = 0.f, pg = 0.f, po = 0.f;
  if (q == 0) {
    pi = px[pxbase + u];        pf = px[pxbase + 256 + u];
    pg = px[pxbase + 512 + u];  po = px[pxbase + 768 + u];
  }

  for (int t = 0; t < SEQ; ++t) {
    const float* __restrict__ hb = hsh[t & 1];
    float*       __restrict__ nb = hsh[(t & 1) ^ 1];

    // prefetch next step's px behind the FMA phase
    float ni = 0.f, nf = 0.f, ng = 0.f, no = 0.f;
    if (q == 0 && t + 1 < SEQ) {
      const size_t nbx = pxbase + (size_t)(t + 1) * GATE;
      ni = px[nbx + u];        nf = px[nbx + 256 + u];
      ng = px[nbx + 512 + u];  no = px[nbx + 768 + u];
    }

    float si = 0.f, sf = 0.f, sg = 0.f, so = 0.f;
    #pragma unroll
    for (int m = 0; m < 8; ++m) {
      const float4 h4 = *reinterpret_cast<const float4*>(&hb[36 * q + 4 * m]);
      si = fmaf(h4.x, wi[m].x, si); si = fmaf(h4.y, wi[m].y, si);
      si = fmaf(h4.z, wi[m].z, si); si = fmaf(h4.w, wi[m].w, si);
      sf = fmaf(h4.x, wf[m].x, sf); sf = fmaf(h4.y, wf[m].y, sf);
      sf = fmaf(h4.z, wf[m].z, sf); sf = fmaf(h4.w, wf[m].w, sf);
      sg = fmaf(h4.x, wg[m].x, sg); sg = fmaf(h4.y, wg[m].y, sg);
      sg = fmaf(h4.z, wg[m].z, sg); sg = fmaf(h4.w, wg[m].w, sg);
      so = fmaf(h4.x, wo[m].x, so); so = fmaf(h4.y, wo[m].y, so);
      so = fmaf(h4.z, wo[m].z, so); so = fmaf(h4.w, wo[m].w, so);
    }
    // reduce the 8 K-slice partials (adjacent lanes) into q==0
    #pragma unroll
    for (int off = 4; off >= 1; off >>= 1) {
      si += __shfl_down(si, off, 8);
      sf += __shfl_down(sf, off, 8);
      sg += __shfl_down(sg, off, 8);
      so += __shfl_down(so, off, 8);
    }

    if (q == 0) {
      const float gi = si + pi, gf = sf + pf, gg = sg + pg, go = so + po;
      const float ai = 1.0f / (1.0f + expf(-gi));
      const float af = 1.0f / (1.0f + expf(-gf));
      const float ao = 1.0f / (1.0f + expf(-go));
      c = af * c + ai * tanhf(gg);
      const float hn = ao * tanhf(c);
      // publish first (critical path), then local LDS + plain copy
      const unsigned long long pk =
          ((unsigned long long)(unsigned)(t + 1) << 32) |
          (unsigned long long)__float_as_uint(hn);
      __hip_atomic_store(&hx[((size_t)dir * SEQ + t) * HID + u], pk,
                         __ATOMIC_RELAXED, __HIP_MEMORY_SCOPE_AGENT);
      nb[36 * b + j] = hn;           // own chunk: no LLC round trip
      hs[((size_t)dir * SEQ + t) * HID + u] = hn;
    }
    pi = ni; pf = nf; pg = ng; po = no;
    if (t == SEQ - 1) break;     // uniform: no one consumes the last broadcast

    // gather the other 224 units' tagged packets from LLC (per-wave ballot,
    // no block barrier in the loop)
    {
      const size_t gidx = ((size_t)dir * SEQ + t) * HID + tid;
      const unsigned want = (unsigned)(t + 1);
      bool need = (tid >> 5) != b;   // own 32 units arrived via LDS
      while (__ballot(need) != 0ULL) {
        if (need) {
          const unsigned long long v = __hip_atomic_load(
              &hx[gidx], __ATOMIC_RELAXED, __HIP_MEMORY_SCOPE_AGENT);
          if ((unsigned)(v >> 32) == want) {
            nb[36 * (tid >> 5) + (tid & 31)] = __uint_as_float((unsigned)v);
            need = false;
          }
        }
      }
    }
    __syncthreads();   // nb fully populated; hb no longer needed
  }
}

// ---------------------------------------------------------------------------
// Kernel 3: feats[t][j] = concat(h_fwd[t], h_bwd[S-1-t]) . w_tag[j] + b_tag[j]
// One block per t; 8 lanes per tag j, shfl-reduce within groups of 8.
// ---------------------------------------------------------------------------
__global__ __launch_bounds__(256) void feats_kernel(
    const float* __restrict__ hs, const float* __restrict__ w_tag,
    const float* __restrict__ b_tag, float* __restrict__ feats)
{
  const int t = blockIdx.x;
  const int tid = threadIdx.x;
  const int j = tid >> 3, p = tid & 7;
  const float* __restrict__ src = (p < 4)
      ? (hs + (size_t)t * HID + p * 64)                              // fwd half
      : (hs + (size_t)(SEQ + (SEQ - 1 - t)) * HID + (p - 4) * 64);   // bwd half
  const float* __restrict__ wt = w_tag + (size_t)j * (2 * HID) + p * 64;
  float sum = 0.f;
  #pragma unroll
  for (int k = 0; k < 64; k += 4) {
    const float4 x4 = *reinterpret_cast<const float4*>(&src[k]);
    const float4 w4 = *reinterpret_cast<const float4*>(&wt[k]);
    sum = fmaf(x4.x, w4.x, sum); sum = fmaf(x4.y, w4.y, sum);
    sum = fmaf(x4.z, w4.z, sum); sum = fmaf(x4.w, w4.w, sum);
  }
  sum += __shfl_down(sum, 4, 8);
  sum += __shfl_down(sum, 2, 8);
  sum += __shfl_down(sum, 1, 8);
  if (p == 0) feats[(size_t)t * NTAG + j] = sum + b_tag[j];
}

// ---------------------------------------------------------------------------
// Kernel 4: Viterbi + backtrace, single wave (64 threads = 1 wave, no
// barriers needed). Lane (j = lane&31, half = lane>>5) scans 16 prev-tags;
// halves merged via shfl. Backpointers in 64 KB LDS; lane 0 backtraces.
// Tie-breaking matches jnp.argmax (first index): strict '>' updates only,
// lower half preferred on ties.
// ---------------------------------------------------------------------------
__global__ __launch_bounds__(64) void viterbi_kernel(
    const float* __restrict__ feats, const float* __restrict__ trans,
    float* __restrict__ out)
{
  __shared__ unsigned char bp[SEQ][NTAG];   // 64 KiB exactly
  const int lane = threadIdx.x;
  const int j = lane & 31, half = lane >> 5;
  float tr[16];
  #pragma unroll
  for (int qq = 0; qq < 16; ++qq) tr[qq] = trans[j * NTAG + half * 16 + qq];
  float fv = (j == 30) ? 0.0f : FNEG;       // START = 30
  float fcur = feats[j];
  for (int t = 0; t < SEQ; ++t) {
    const int tn = (t + 1 < SEQ) ? (t + 1) : (SEQ - 1);
    const float fnext = feats[(size_t)tn * NTAG + j];
    float best = -3.0e38f; int barg = 0;
    #pragma unroll
    for (int qq = 0; qq < 16; ++qq) {
      const int p = half * 16 + qq;
      const float sc = __shfl(fv, p) + tr[qq];
      if (sc > best) { best = sc; barg = p; }
    }
    const float ob = __shfl_down(best, 32);
    const int   oa = __shfl_down(barg, 32);
    float fvnew = 0.f;
    if (half == 0) {
      if (ob > best) { best = ob; barg = oa; }
      bp[t][j] = (unsigned char)barg;
      fvnew = best + fcur;
    }
    fv = __shfl(fvnew, j);   // broadcast updated fv[j] to both halves
    fcur = fnext;
  }
  float term = fv + trans[31 * NTAG + j];   // STOP = 31
  int idx = j;
  #pragma unroll
  for (int off = 16; off >= 1; off >>= 1) {
    const float ov = __shfl_down(term, off, 32);
    const int   oi = __shfl_down(idx, off, 32);
    if (ov > term) { term = ov; idx = oi; }
  }
  if (lane == 0) {
    out[0] = term;                 // path score
    int tag = idx;
    for (int t = SEQ - 1; t >= 0; --t) {
      out[1 + t] = (float)tag;     // y[S-1] = best_last; y[t] = bp[t+1][y[t+1]]
      tag = bp[t][tag];
    }
  }
}

// ---------------------------------------------------------------------------
extern "C" void kernel_launch(void* const* d_in, const int* in_sizes, int n_in,
                              void* d_out, int out_size, void* d_ws, size_t ws_size,
                              hipStream_t stream)
{
  (void)in_sizes; (void)n_in; (void)out_size; (void)ws_size;
  const int*   sent   = (const int*)  d_in[0];
  const float* embed  = (const float*)d_in[1];
  const float* w_ih_f = (const float*)d_in[2];
  const float* w_hh_f = (const float*)d_in[3];
  const float* b_f    = (const float*)d_in[4];
  const float* w_ih_b = (const float*)d_in[5];
  const float* w_hh_b = (const float*)d_in[6];
  const float* b_b    = (const float*)d_in[7];
  const float* w_tag  = (const float*)d_in[8];
  const float* b_tag  = (const float*)d_in[9];
  const float* trans  = (const float*)d_in[10];
  const float* h0     = (const float*)d_in[11];
  const float* c0     = (const float*)d_in[12];
  float* out = (float*)d_out;

  // workspace (d_ws): hx[2][S][256] u64 | px[2][S][1024] | hs[2][S][256] | feats[S][32]
  unsigned long long* hx = (unsigned long long*)d_ws;          // 8 MB, 8B-aligned
  float* px    = (float*)(hx + (size_t)2 * SEQ * HID);         // 16 MB
  float* hsbuf = px + (size_t)2 * SEQ * GATE;                  // 4 MB
  float* feats = hsbuf + (size_t)2 * SEQ * HID;                // 256 KB

  dim3 gemm_grid(SEQ / 64, GATE / 64, 2);
  px_gemm<<<gemm_grid, 256, 0, stream>>>(sent, embed, w_ih_f, b_f,
                                         w_ih_b, b_b, px);
  lstm_sync<<<2 * DBLK, 256, 0, stream>>>(px, w_hh_f, w_hh_b, h0, c0,
                                          hsbuf, hx);
  feats_kernel<<<SEQ, 256, 0, stream>>>(hsbuf, w_tag, b_tag, feats);
  viterbi_kernel<<<1, 64, 0, stream>>>(feats, trans, out);
}

// Round 4
// 6210.108 us; speedup vs baseline: 6.2200x; 1.0008x over previous
//
#include <hip/hip_runtime.h>
#include <cstdint>
#include <cmath>

// Problem constants
constexpr int SEQ  = 2048;   // sequence length S
constexpr int EMB  = 512;    // embed dim E
constexpr int HID  = 256;    // per-direction hidden H
constexpr int GATE = 1024;   // 4*H
constexpr int NTAG = 32;     // tagset T
constexpr float FNEG = -10000.0f;
constexpr int DBLK = 8;      // blocks per direction for the LSTM

// ---------------------------------------------------------------------------
// Kernel 1: px[dir][s][j] = emb[t_eff(dir,s)] . w_ih_dir[j] + b_dir[j]
// Tiled fp32 GEMM, 64x64 tile, K-tile 64, 256 threads, 4x4 acc per thread.
// dir==1 uses the reversed sequence (backward LSTM consumes emb[S-1-s]).
// ---------------------------------------------------------------------------
__global__ __launch_bounds__(256) void px_gemm(
    const int* __restrict__ sent, const float* __restrict__ embed,
    const float* __restrict__ w_ih_f, const float* __restrict__ b_f,
    const float* __restrict__ w_ih_b, const float* __restrict__ b_b,
    float* __restrict__ px)
{
  const int dir = blockIdx.z;
  const int tm = blockIdx.x, tn = blockIdx.y;
  const float* __restrict__ w_ih = dir ? w_ih_b : w_ih_f;
  const float* __restrict__ bias = dir ? b_b : b_f;
  __shared__ float As[64][65];   // +1 pad -> 2-way max bank aliasing (free)
  __shared__ float Bs[64][65];
  __shared__ int sidx[64];
  const int tid = threadIdx.x;
  if (tid < 64) {
    const int s = tm * 64 + tid;
    const int tpos = dir ? (SEQ - 1 - s) : s;
    sidx[tid] = sent[tpos];
  }
  __syncthreads();
  float acc[4][4] = {};
  const int tr = tid >> 4, tc = tid & 15;
  for (int k0 = 0; k0 < EMB; k0 += 64) {
    #pragma unroll
    for (int i = 0; i < 4; ++i) {
      const int v = tid + i * 256;           // 1024 float4 slots: 64 rows x 16
      const int r = v >> 4, kv = v & 15;
      const float4 a4 = *reinterpret_cast<const float4*>(
          &embed[(size_t)sidx[r] * EMB + k0 + kv * 4]);
      As[r][kv*4+0] = a4.x; As[r][kv*4+1] = a4.y;
      As[r][kv*4+2] = a4.z; As[r][kv*4+3] = a4.w;
      const float4 b4 = *reinterpret_cast<const float4*>(
          &w_ih[(size_t)(tn * 64 + r) * EMB + k0 + kv * 4]);
      Bs[r][kv*4+0] = b4.x; Bs[r][kv*4+1] = b4.y;
      Bs[r][kv*4+2] = b4.z; Bs[r][kv*4+3] = b4.w;
    }
    __syncthreads();
    #pragma unroll
    for (int kk = 0; kk < 64; ++kk) {
      float a[4], b[4];
      #pragma unroll
      for (int i = 0; i < 4; ++i) a[i] = As[tr + 16 * i][kk];
      #pragma unroll
      for (int jj = 0; jj < 4; ++jj) b[jj] = Bs[tc + 16 * jj][kk];
      #pragma unroll
      for (int i = 0; i < 4; ++i)
        #pragma unroll
        for (int jj = 0; jj < 4; ++jj)
          acc[i][jj] = fmaf(a[i], b[jj], acc[i][jj]);
    }
    __syncthreads();
  }
  #pragma unroll
  for (int i = 0; i < 4; ++i) {
    const int srow = tm * 64 + tr + 16 * i;
    #pragma unroll
    for (int jj = 0; jj < 4; ++jj) {
      const int j = tn * 64 + tc + 16 * jj;   // tc fastest -> coalesced stores
      px[((size_t)dir * SEQ + srow) * GATE + j] = acc[i][jj] + bias[j];
    }
  }
}

// ---------------------------------------------------------------------------
// Kernel 2: LSTM recurrence, 2 x DBLK blocks of 256 threads (one CU each).
// R3 lesson: even at waves_per_eu(1,1) (512-VGPR budget) the scheduler SANK
// the 128 loop-invariant weight loads into the t-loop (VGPR_Count=132 -> the
// block re-streamed 128 KB/step from L2, ~2300 cyc/step). Fix: an empty
// `asm volatile` consuming+redefining every weight float right after the
// load. The asm becomes the SSA definition point -- the loads cannot sink or
// rematerialize; values must stay in VGPRs (budget 512 holds ~170, no spill).
// Layout: thread (j = tid>>3, q = tid&7) owns unit u=32b+j, K-slice
// [32q,32q+32): 4 gate rows x 32 cols = 32 float4 registers. Gate partials
// shfl-reduce over the 8 adjacent lanes; cell state c lives in lane q==0.
// Cross-block h broadcast: self-tagged 8B packets (epoch=t+1 | h bits) via
// agent-scope atomics (LLC-coherent; per-XCD L2s are NOT cross-coherent).
// Poison 0xAA never aliases an epoch -> no flags, no memset, graph-safe.
// Per-wave ballot polling with s_sleep(1) backoff between failed rounds
// (3584 lanes tight-spinning on LLC inflates queue latency); own block's 32
// units go straight to LDS; h double-buffered on t-parity -> ONE
// __syncthreads per step.
// ---------------------------------------------------------------------------
__global__ __attribute__((amdgpu_flat_work_group_size(256, 256),
                          amdgpu_waves_per_eu(1, 1)))
void lstm_sync(
    const float* __restrict__ px, const float* __restrict__ w_hh_f,
    const float* __restrict__ w_hh_b, const float* __restrict__ h0,
    const float* __restrict__ c0, float* __restrict__ hs,
    unsigned long long* __restrict__ hx)
{
  const int blk = blockIdx.x;
  const int dir = blk >> 3, b = blk & 7;
  const int tid = threadIdx.x;
  const int j = tid >> 3;          // unit within block's 32
  const int q = tid & 7;           // K-slice index (32 floats each)
  const int u = 32 * b + j;        // global hidden unit
  const float* __restrict__ w_hh = dir ? w_hh_b : w_hh_f;

  // Weight fragments: rows u, 256+u, 512+u, 768+u; cols [32q, 32q+32)
  float4 wi[8], wf[8], wg[8], wo[8];
  {
    const float* __restrict__ r0 = &w_hh[(size_t)u * HID + 32 * q];
    const float* __restrict__ r1 = r0 + (size_t)256 * HID;
    const float* __restrict__ r2 = r0 + (size_t)512 * HID;
    const float* __restrict__ r3 = r0 + (size_t)768 * HID;
    #pragma unroll
    for (int m = 0; m < 8; ++m) {
      wi[m] = *reinterpret_cast<const float4*>(&r0[4 * m]);
      wf[m] = *reinterpret_cast<const float4*>(&r1[4 * m]);
      wg[m] = *reinterpret_cast<const float4*>(&r2[4 * m]);
      wo[m] = *reinterpret_cast<const float4*>(&r3[4 * m]);
    }
  }
  // Pin all 128 weight floats in VGPRs: the asm is volatile and redefines
  // each value, so the global loads above must execute exactly once, here.
  #pragma unroll
  for (int m = 0; m < 8; ++m) {
    asm volatile(""
      : "+v"(wi[m].x), "+v"(wi[m].y), "+v"(wi[m].z), "+v"(wi[m].w),
        "+v"(wf[m].x), "+v"(wf[m].y), "+v"(wf[m].z), "+v"(wf[m].w),
        "+v"(wg[m].x), "+v"(wg[m].y), "+v"(wg[m].z), "+v"(wg[m].w),
        "+v"(wo[m].x), "+v"(wo[m].y), "+v"(wo[m].z), "+v"(wo[m].w));
  }

  // h double-buffered; chunk q at 36q (bank-spread pad, conflict-free b128)
  __shared__ float hsh[2][8 * 36];
  float c = 0.0f;
  hsh[0][36 * (tid >> 5) + (tid & 31)] = h0[dir * HID + tid];
  if (q == 0) c = c0[dir * HID + u];
  __syncthreads();

  const size_t pxbase = (size_t)dir * SEQ * GATE;
  float pi = 0.f, pf = 0.f, pg = 0.f, po = 0.f;
  if (q == 0) {
    pi = px[pxbase + u];        pf = px[pxbase + 256 + u];
    pg = px[pxbase + 512 + u];  po = px[pxbase + 768 + u];
  }

  for (int t = 0; t < SEQ; ++t) {
    const float* __restrict__ hb = hsh[t & 1];
    float*       __restrict__ nb = hsh[(t & 1) ^ 1];

    // prefetch next step's px behind the FMA phase
    float ni = 0.f, nf = 0.f, ng = 0.f, no = 0.f;
    if (q == 0 && t + 1 < SEQ) {
      const size_t nbx = pxbase + (size_t)(t + 1) * GATE;
      ni = px[nbx + u];        nf = px[nbx + 256 + u];
      ng = px[nbx + 512 + u];  no = px[nbx + 768 + u];
    }

    float si = 0.f, sf = 0.f, sg = 0.f, so = 0.f;
    #pragma unroll
    for (int m = 0; m < 8; ++m) {
      const float4 h4 = *reinterpret_cast<const float4*>(&hb[36 * q + 4 * m]);
      si = fmaf(h4.x, wi[m].x, si); si = fmaf(h4.y, wi[m].y, si);
      si = fmaf(h4.z, wi[m].z, si); si = fmaf(h4.w, wi[m].w, si);
      sf = fmaf(h4.x, wf[m].x, sf); sf = fmaf(h4.y, wf[m].y, sf);
      sf = fmaf(h4.z, wf[m].z, sf); sf = fmaf(h4.w, wf[m].w, sf);
      sg = fmaf(h4.x, wg[m].x, sg); sg = fmaf(h4.y, wg[m].y, sg);
      sg = fmaf(h4.z, wg[m].z, sg); sg = fmaf(h4.w, wg[m].w, sg);
      so = fmaf(h4.x, wo[m].x, so); so = fmaf(h4.y, wo[m].y, so);
      so = fmaf(h4.z, wo[m].z, so); so = fmaf(h4.w, wo[m].w, so);
    }
    // reduce the 8 K-slice partials (adjacent lanes) into q==0
    #pragma unroll
    for (int off = 4; off >= 1; off >>= 1) {
      si += __shfl_down(si, off, 8);
      sf += __shfl_down(sf, off, 8);
      sg += __shfl_down(sg, off, 8);
      so += __shfl_down(so, off, 8);
    }

    if (q == 0) {
      const float gi = si + pi, gf = sf + pf, gg = sg + pg, go = so + po;
      const float ai = 1.0f / (1.0f + expf(-gi));
      const float af = 1.0f / (1.0f + expf(-gf));
      const float ao = 1.0f / (1.0f + expf(-go));
      c = af * c + ai * tanhf(gg);
      const float hn = ao * tanhf(c);
      // publish first (critical path), then local LDS + plain copy
      const unsigned long long pk =
          ((unsigned long long)(unsigned)(t + 1) << 32) |
          (unsigned long long)__float_as_uint(hn);
      __hip_atomic_store(&hx[((size_t)dir * SEQ + t) * HID + u], pk,
                         __ATOMIC_RELAXED, __HIP_MEMORY_SCOPE_AGENT);
      nb[36 * b + j] = hn;           // own chunk: no LLC round trip
      hs[((size_t)dir * SEQ + t) * HID + u] = hn;
    }
    pi = ni; pf = nf; pg = ng; po = no;
    if (t == SEQ - 1) break;     // uniform: no one consumes the last broadcast

    // gather the other 224 units' tagged packets from LLC (per-wave ballot;
    // s_sleep backoff only after a failed round, success path unpenalized)
    {
      const size_t gidx = ((size_t)dir * SEQ + t) * HID + tid;
      const unsigned want = (unsigned)(t + 1);
      bool need = (tid >> 5) != b;   // own 32 units arrived via LDS
      while (true) {
        if (need) {
          const unsigned long long v = __hip_atomic_load(
              &hx[gidx], __ATOMIC_RELAXED, __HIP_MEMORY_SCOPE_AGENT);
          if ((unsigned)(v >> 32) == want) {
            nb[36 * (tid >> 5) + (tid & 31)] = __uint_as_float((unsigned)v);
            need = false;
          }
        }
        if (__ballot(need) == 0ULL) break;
        __builtin_amdgcn_s_sleep(1);
      }
    }
    __syncthreads();   // nb fully populated; hb no longer needed
  }
}

// ---------------------------------------------------------------------------
// Kernel 3: feats[t][j] = concat(h_fwd[t], h_bwd[S-1-t]) . w_tag[j] + b_tag[j]
// One block per t; 8 lanes per tag j, shfl-reduce within groups of 8.
// ---------------------------------------------------------------------------
__global__ __launch_bounds__(256) void feats_kernel(
    const float* __restrict__ hs, const float* __restrict__ w_tag,
    const float* __restrict__ b_tag, float* __restrict__ feats)
{
  const int t = blockIdx.x;
  const int tid = threadIdx.x;
  const int j = tid >> 3, p = tid & 7;
  const float* __restrict__ src = (p < 4)
      ? (hs + (size_t)t * HID + p * 64)                              // fwd half
      : (hs + (size_t)(SEQ + (SEQ - 1 - t)) * HID + (p - 4) * 64);   // bwd half
  const float* __restrict__ wt = w_tag + (size_t)j * (2 * HID) + p * 64;
  float sum = 0.f;
  #pragma unroll
  for (int k = 0; k < 64; k += 4) {
    const float4 x4 = *reinterpret_cast<const float4*>(&src[k]);
    const float4 w4 = *reinterpret_cast<const float4*>(&wt[k]);
    sum = fmaf(x4.x, w4.x, sum); sum = fmaf(x4.y, w4.y, sum);
    sum = fmaf(x4.z, w4.z, sum); sum = fmaf(x4.w, w4.w, sum);
  }
  sum += __shfl_down(sum, 4, 8);
  sum += __shfl_down(sum, 2, 8);
  sum += __shfl_down(sum, 1, 8);
  if (p == 0) feats[(size_t)t * NTAG + j] = sum + b_tag[j];
}

// ---------------------------------------------------------------------------
// Kernel 4: Viterbi + backtrace, single wave (64 threads = 1 wave, no
// barriers needed). Lane (j = lane&31, half = lane>>5) scans 16 prev-tags;
// halves merged via shfl. Backpointers in 64 KB LDS; lane 0 backtraces.
// Tie-breaking matches jnp.argmax (first index): strict '>' updates only,
// lower half preferred on ties.
// ---------------------------------------------------------------------------
__global__ __launch_bounds__(64) void viterbi_kernel(
    const float* __restrict__ feats, const float* __restrict__ trans,
    float* __restrict__ out)
{
  __shared__ unsigned char bp[SEQ][NTAG];   // 64 KiB exactly
  const int lane = threadIdx.x;
  const int j = lane & 31, half = lane >> 5;
  float tr[16];
  #pragma unroll
  for (int qq = 0; qq < 16; ++qq) tr[qq] = trans[j * NTAG + half * 16 + qq];
  float fv = (j == 30) ? 0.0f : FNEG;       // START = 30
  float fcur = feats[j];
  for (int t = 0; t < SEQ; ++t) {
    const int tn = (t + 1 < SEQ) ? (t + 1) : (SEQ - 1);
    const float fnext = feats[(size_t)tn * NTAG + j];
    float best = -3.0e38f; int barg = 0;
    #pragma unroll
    for (int qq = 0; qq < 16; ++qq) {
      const int p = half * 16 + qq;
      const float sc = __shfl(fv, p) + tr[qq];
      if (sc > best) { best = sc; barg = p; }
    }
    const float ob = __shfl_down(best, 32);
    const int   oa = __shfl_down(barg, 32);
    float fvnew = 0.f;
    if (half == 0) {
      if (ob > best) { best = ob; barg = oa; }
      bp[t][j] = (unsigned char)barg;
      fvnew = best + fcur;
    }
    fv = __shfl(fvnew, j);   // broadcast updated fv[j] to both halves
    fcur = fnext;
  }
  float term = fv + trans[31 * NTAG + j];   // STOP = 31
  int idx = j;
  #pragma unroll
  for (int off = 16; off >= 1; off >>= 1) {
    const float ov = __shfl_down(term, off, 32);
    const int   oi = __shfl_down(idx, off, 32);
    if (ov > term) { term = ov; idx = oi; }
  }
  if (lane == 0) {
    out[0] = term;                 // path score
    int tag = idx;
    for (int t = SEQ - 1; t >= 0; --t) {
      out[1 + t] = (float)tag;     // y[S-1] = best_last; y[t] = bp[t+1][y[t+1]]
      tag = bp[t][tag];
    }
  }
}

// ---------------------------------------------------------------------------
extern "C" void kernel_launch(void* const* d_in, const int* in_sizes, int n_in,
                              void* d_out, int out_size, void* d_ws, size_t ws_size,
                              hipStream_t stream)
{
  (void)in_sizes; (void)n_in; (void)out_size; (void)ws_size;
  const int*   sent   = (const int*)  d_in[0];
  const float* embed  = (const float*)d_in[1];
  const float* w_ih_f = (const float*)d_in[2];
  const float* w_hh_f = (const float*)d_in[3];
  const float* b_f    = (const float*)d_in[4];
  const float* w_ih_b = (const float*)d_in[5];
  const float* w_hh_b = (const float*)d_in[6];
  const float* b_b    = (const float*)d_in[7];
  const float* w_tag  = (const float*)d_in[8];
  const float* b_tag  = (const float*)d_in[9];
  const float* trans  = (const float*)d_in[10];
  const float* h0     = (const float*)d_in[11];
  const float* c0     = (const float*)d_in[12];
  float* out = (float*)d_out;

  // workspace (d_ws): hx[2][S][256] u64 | px[2][S][1024] | hs[2][S][256] | feats[S][32]
  unsigned long long* hx = (unsigned long long*)d_ws;          // 8 MB, 8B-aligned
  float* px    = (float*)(hx + (size_t)2 * SEQ * HID);         // 16 MB
  float* hsbuf = px + (size_t)2 * SEQ * GATE;                  // 4 MB
  float* feats = hsbuf + (size_t)2 * SEQ * HID;                // 256 KB

  dim3 gemm_grid(SEQ / 64, GATE / 64, 2);
  px_gemm<<<gemm_grid, 256, 0, stream>>>(sent, embed, w_ih_f, b_f,
                                         w_ih_b, b_b, px);
  lstm_sync<<<2 * DBLK, 256, 0, stream>>>(px, w_hh_f, w_hh_b, h0, c0,
                                          hsbuf, hx);
  feats_kernel<<<SEQ, 256, 0, stream>>>(hsbuf, w_tag, b_tag, feats);
  viterbi_kernel<<<1, 64, 0, stream>>>(feats, trans, out);
}

// Round 5
// 5484.536 us; speedup vs baseline: 7.0429x; 1.1323x over previous
//
#include <hip/hip_runtime.h>
#include <cstdint>
#include <cmath>

// Problem constants
constexpr int SEQ  = 2048;   // sequence length S
constexpr int EMB  = 512;    // embed dim E
constexpr int HID  = 256;    // per-direction hidden H
constexpr int GATE = 1024;   // 4*H
constexpr int NTAG = 32;     // tagset T
constexpr float FNEG = -10000.0f;
constexpr int NBLK = 128;    // launched LSTM blocks (workers self-select)
constexpr int NWORK = 16;    // 8 blocks per direction actually work

// ---------------------------------------------------------------------------
// Kernel 1: px[dir][s][j] = emb[t_eff(dir,s)] . w_ih_dir[j] + b_dir[j]
// Tiled fp32 GEMM, 64x64 tile, K-tile 64, 256 threads, 4x4 acc per thread.
// ---------------------------------------------------------------------------
__global__ __launch_bounds__(256) void px_gemm(
    const int* __restrict__ sent, const float* __restrict__ embed,
    const float* __restrict__ w_ih_f, const float* __restrict__ b_f,
    const float* __restrict__ w_ih_b, const float* __restrict__ b_b,
    float* __restrict__ px)
{
  const int dir = blockIdx.z;
  const int tm = blockIdx.x, tn = blockIdx.y;
  const float* __restrict__ w_ih = dir ? w_ih_b : w_ih_f;
  const float* __restrict__ bias = dir ? b_b : b_f;
  __shared__ float As[64][65];   // +1 pad -> 2-way max bank aliasing (free)
  __shared__ float Bs[64][65];
  __shared__ int sidx[64];
  const int tid = threadIdx.x;
  if (tid < 64) {
    const int s = tm * 64 + tid;
    const int tpos = dir ? (SEQ - 1 - s) : s;
    sidx[tid] = sent[tpos];
  }
  __syncthreads();
  float acc[4][4] = {};
  const int tr = tid >> 4, tc = tid & 15;
  for (int k0 = 0; k0 < EMB; k0 += 64) {
    #pragma unroll
    for (int i = 0; i < 4; ++i) {
      const int v = tid + i * 256;           // 1024 float4 slots: 64 rows x 16
      const int r = v >> 4, kv = v & 15;
      const float4 a4 = *reinterpret_cast<const float4*>(
          &embed[(size_t)sidx[r] * EMB + k0 + kv * 4]);
      As[r][kv*4+0] = a4.x; As[r][kv*4+1] = a4.y;
      As[r][kv*4+2] = a4.z; As[r][kv*4+3] = a4.w;
      const float4 b4 = *reinterpret_cast<const float4*>(
          &w_ih[(size_t)(tn * 64 + r) * EMB + k0 + kv * 4]);
      Bs[r][kv*4+0] = b4.x; Bs[r][kv*4+1] = b4.y;
      Bs[r][kv*4+2] = b4.z; Bs[r][kv*4+3] = b4.w;
    }
    __syncthreads();
    #pragma unroll
    for (int kk = 0; kk < 64; ++kk) {
      float a[4], b[4];
      #pragma unroll
      for (int i = 0; i < 4; ++i) a[i] = As[tr + 16 * i][kk];
      #pragma unroll
      for (int jj = 0; jj < 4; ++jj) b[jj] = Bs[tc + 16 * jj][kk];
      #pragma unroll
      for (int i = 0; i < 4; ++i)
        #pragma unroll
        for (int jj = 0; jj < 4; ++jj)
          acc[i][jj] = fmaf(a[i], b[jj], acc[i][jj]);
    }
    __syncthreads();
  }
  #pragma unroll
  for (int i = 0; i < 4; ++i) {
    const int srow = tm * 64 + tr + 16 * i;
    #pragma unroll
    for (int jj = 0; jj < 4; ++jj) {
      const int j = tn * 64 + tc + 16 * jj;   // tc fastest -> coalesced stores
      px[((size_t)dir * SEQ + srow) * GATE + j] = acc[i][jj] + bias[j];
    }
  }
}

// ---------------------------------------------------------------------------
// ctl[0]=reg_count ctl[1..8]=xcd_count ctl[9]=chosen(0x100|xcd) ctl[10]=claim
// Zeroed by init_ctl each launch (poison 0xAA never aliases a valid state).
// ---------------------------------------------------------------------------
__global__ void init_ctl(unsigned* ctl) {
  if (threadIdx.x < 16) ctl[threadIdx.x] = 0u;
}

// sc0 load: bypass L1, served by this XCD's L2 (coherent intra-XCD).
__device__ __forceinline__ unsigned long long ld_l2(
    const unsigned long long* p) {
  unsigned long long v;
  asm volatile("global_load_dwordx2 %0, %1, off sc0\n\ts_waitcnt vmcnt(0)"
               : "=v"(v) : "v"(p) : "memory");
  return v;
}
// sc0+sc1 load: bypass L1 and L2, read LLC (device-correct fallback).
__device__ __forceinline__ unsigned long long ld_llc(
    const unsigned long long* p) {
  unsigned long long v;
  asm volatile("global_load_dwordx2 %0, %1, off sc0 sc1\n\ts_waitcnt vmcnt(0)"
               : "=v"(v) : "v"(p) : "memory");
  return v;
}

// ---------------------------------------------------------------------------
// Kernel 2: LSTM recurrence. R4 post-mortem: step time (5800 cyc) is pure
// sync latency -- every poll is an agent-scope LLC round trip (~700-900 cyc,
// 2-3 serial rounds; FETCH_SIZE 46 MB == exactly the poll traffic). Fix:
// co-locate all 16 workers on ONE XCD and poll through its coherent L2
// (~200-300 cyc). Placement protocol (correct under arbitrary scheduling):
// 128 blocks register their XCD (s_getreg HW_REG_XCC_ID, m09-verified);
// block 0 waits for all 128 (co-resident: 128 <= 256 CUs), picks the XCD
// with the most blocks (pigeonhole >= 16), publishes; first 16 claimers on
// that XCD work (dir=idx>>3, b=idx&7), rest exit.
// Publishes: agent-scope atomic store (write-through L2 AND LLC) -- correct
// for any reader. Polls: sc0 (L2) fast path; sticky per-lane fallback to
// sc0+sc1 (LLC) after 200 failed rounds -> placement failure degrades to
// R4 speed instead of deadlocking (Guideline 16).
// Compute layout unchanged from R2-R4 (absmax 0.0): thread (j=tid>>3,q=tid&7)
// owns unit u=32b+j, K-slice [32q,32q+32) in 32 float4 regs; shfl-reduce over
// 8 lanes; c in lane q==0; h double-buffered in LDS, one barrier per step.
// ---------------------------------------------------------------------------
__global__ __attribute__((amdgpu_flat_work_group_size(256, 256),
                          amdgpu_waves_per_eu(1, 1)))
void lstm_xcd(
    const float* __restrict__ px, const float* __restrict__ w_hh_f,
    const float* __restrict__ w_hh_b, const float* __restrict__ h0,
    const float* __restrict__ c0, float* __restrict__ hs,
    unsigned long long* __restrict__ hx, unsigned* __restrict__ ctl)
{
  const int tid = threadIdx.x;
  __shared__ int s_asn;
  if (tid == 0) {
    // HW_REG_XCC_ID: id=20, offset=0, size=32 -> imm 63508 [m09]
    unsigned xcd = __builtin_amdgcn_s_getreg(63508) & 7u;
    atomicAdd(&ctl[1 + xcd], 1u);
    __threadfence();
    atomicAdd(&ctl[0], 1u);
    if (blockIdx.x == 0) {
      while (__hip_atomic_load(&ctl[0], __ATOMIC_RELAXED,
                               __HIP_MEMORY_SCOPE_AGENT) < (unsigned)NBLK)
        __builtin_amdgcn_s_sleep(16);
      __threadfence();
      unsigned best = 0, bc = 0;
      for (unsigned x = 0; x < 8; ++x) {
        const unsigned cx = __hip_atomic_load(&ctl[1 + x], __ATOMIC_RELAXED,
                                              __HIP_MEMORY_SCOPE_AGENT);
        if (cx > bc) { bc = cx; best = x; }
      }
      __hip_atomic_store(&ctl[9], 0x100u | best, __ATOMIC_RELAXED,
                         __HIP_MEMORY_SCOPE_AGENT);
    }
    unsigned ch;
    while (((ch = __hip_atomic_load(&ctl[9], __ATOMIC_RELAXED,
                                    __HIP_MEMORY_SCOPE_AGENT)) & 0x100u) == 0)
      __builtin_amdgcn_s_sleep(16);
    int mine = -1;
    if ((ch & 7u) == xcd) {
      const unsigned idx = atomicAdd(&ctl[10], 1u);
      if (idx < (unsigned)NWORK) mine = (int)idx;
    }
    s_asn = mine;
  }
  __syncthreads();
  const int asn = s_asn;
  if (asn < 0) return;                      // non-worker: uniform exit
  const int dir = asn >> 3, b = asn & 7;

  const int j = tid >> 3;          // unit within block's 32
  const int q = tid & 7;           // K-slice index (32 floats each)
  const int u = 32 * b + j;        // global hidden unit
  const float* __restrict__ w_hh = dir ? w_hh_b : w_hh_f;

  // Weight fragments: rows u, 256+u, 512+u, 768+u; cols [32q, 32q+32)
  float4 wi[8], wf[8], wg[8], wo[8];
  {
    const float* __restrict__ r0 = &w_hh[(size_t)u * HID + 32 * q];
    const float* __restrict__ r1 = r0 + (size_t)256 * HID;
    const float* __restrict__ r2 = r0 + (size_t)512 * HID;
    const float* __restrict__ r3 = r0 + (size_t)768 * HID;
    #pragma unroll
    for (int m = 0; m < 8; ++m) {
      wi[m] = *reinterpret_cast<const float4*>(&r0[4 * m]);
      wf[m] = *reinterpret_cast<const float4*>(&r1[4 * m]);
      wg[m] = *reinterpret_cast<const float4*>(&r2[4 * m]);
      wo[m] = *reinterpret_cast<const float4*>(&r3[4 * m]);
    }
  }
  #pragma unroll
  for (int m = 0; m < 8; ++m) {
    asm volatile(""
      : "+v"(wi[m].x), "+v"(wi[m].y), "+v"(wi[m].z), "+v"(wi[m].w),
        "+v"(wf[m].x), "+v"(wf[m].y), "+v"(wf[m].z), "+v"(wf[m].w),
        "+v"(wg[m].x), "+v"(wg[m].y), "+v"(wg[m].z), "+v"(wg[m].w),
        "+v"(wo[m].x), "+v"(wo[m].y), "+v"(wo[m].z), "+v"(wo[m].w));
  }

  // h double-buffered; chunk g at 36g (bank-spread pad, conflict-free b128)
  __shared__ float hsh[2][8 * 36];
  float c = 0.0f;
  hsh[0][36 * (tid >> 5) + (tid & 31)] = h0[dir * HID + tid];
  if (q == 0) c = c0[dir * HID + u];
  __syncthreads();

  const size_t pxbase = (size_t)dir * SEQ * GATE;
  float pi = 0.f, pf = 0.f, pg = 0.f, po = 0.f;
  if (q == 0) {
    pi = px[pxbase + u];        pf = px[pxbase + 256 + u];
    pg = px[pxbase + 512 + u];  po = px[pxbase + 768 + u];
  }

  bool fast = true;   // sticky: demoted to LLC polling if L2 path stalls
  for (int t = 0; t < SEQ; ++t) {
    const float* __restrict__ hb = hsh[t & 1];
    float*       __restrict__ nb = hsh[(t & 1) ^ 1];

    // prefetch next step's px behind the FMA phase
    float ni = 0.f, nf = 0.f, ng = 0.f, no = 0.f;
    if (q == 0 && t + 1 < SEQ) {
      const size_t nbx = pxbase + (size_t)(t + 1) * GATE;
      ni = px[nbx + u];        nf = px[nbx + 256 + u];
      ng = px[nbx + 512 + u];  no = px[nbx + 768 + u];
    }

    float si = 0.f, sf = 0.f, sg = 0.f, so = 0.f;
    #pragma unroll
    for (int m = 0; m < 8; ++m) {
      const float4 h4 = *reinterpret_cast<const float4*>(&hb[36 * q + 4 * m]);
      si = fmaf(h4.x, wi[m].x, si); si = fmaf(h4.y, wi[m].y, si);
      si = fmaf(h4.z, wi[m].z, si); si = fmaf(h4.w, wi[m].w, si);
      sf = fmaf(h4.x, wf[m].x, sf); sf = fmaf(h4.y, wf[m].y, sf);
      sf = fmaf(h4.z, wf[m].z, sf); sf = fmaf(h4.w, wf[m].w, sf);
      sg = fmaf(h4.x, wg[m].x, sg); sg = fmaf(h4.y, wg[m].y, sg);
      sg = fmaf(h4.z, wg[m].z, sg); sg = fmaf(h4.w, wg[m].w, sg);
      so = fmaf(h4.x, wo[m].x, so); so = fmaf(h4.y, wo[m].y, so);
      so = fmaf(h4.z, wo[m].z, so); so = fmaf(h4.w, wo[m].w, so);
    }
    #pragma unroll
    for (int off = 4; off >= 1; off >>= 1) {
      si += __shfl_down(si, off, 8);
      sf += __shfl_down(sf, off, 8);
      sg += __shfl_down(sg, off, 8);
      so += __shfl_down(so, off, 8);
    }

    if (q == 0) {
      const float gi = si + pi, gf = sf + pf, gg = sg + pg, go = so + po;
      const float ai = 1.0f / (1.0f + expf(-gi));
      const float af = 1.0f / (1.0f + expf(-gf));
      const float ao = 1.0f / (1.0f + expf(-go));
      c = af * c + ai * tanhf(gg);
      const float hn = ao * tanhf(c);
      // agent-scope store writes through L2 (fast same-XCD readers) AND LLC
      const unsigned long long pk =
          ((unsigned long long)(unsigned)(t + 1) << 32) |
          (unsigned long long)__float_as_uint(hn);
      __hip_atomic_store(&hx[((size_t)dir * SEQ + t) * HID + u], pk,
                         __ATOMIC_RELAXED, __HIP_MEMORY_SCOPE_AGENT);
      nb[36 * b + j] = hn;           // own chunk: LDS direct
      hs[((size_t)dir * SEQ + t) * HID + u] = hn;
    }
    pi = ni; pf = nf; pg = ng; po = no;
    if (t == SEQ - 1) break;     // uniform: no one consumes the last broadcast

    // gather the other 224 units' tagged packets (L2 fast path)
    {
      const unsigned long long* pp = &hx[((size_t)dir * SEQ + t) * HID + tid];
      const unsigned want = (unsigned)(t + 1);
      bool need = (tid >> 5) != b;   // own 32 units arrived via LDS
      int rounds = 0;
      while (true) {
        if (need) {
          const unsigned long long v = fast ? ld_l2(pp) : ld_llc(pp);
          if ((unsigned)(v >> 32) == want) {
            nb[36 * (tid >> 5) + (tid & 31)] = __uint_as_float((unsigned)v);
            need = false;
          }
        }
        if (__ballot(need) == 0ULL) break;
        ++rounds;
        if (rounds > 200) fast = false;   // misplaced: demote to LLC polling
        if (rounds > 4) __builtin_amdgcn_s_sleep(1);
      }
    }
    __syncthreads();   // nb fully populated; hb no longer needed
  }
}

// ---------------------------------------------------------------------------
// Kernel 3: feats[t][j] = concat(h_fwd[t], h_bwd[S-1-t]) . w_tag[j] + b_tag[j]
// ---------------------------------------------------------------------------
__global__ __launch_bounds__(256) void feats_kernel(
    const float* __restrict__ hs, const float* __restrict__ w_tag,
    const float* __restrict__ b_tag, float* __restrict__ feats)
{
  const int t = blockIdx.x;
  const int tid = threadIdx.x;
  const int j = tid >> 3, p = tid & 7;
  const float* __restrict__ src = (p < 4)
      ? (hs + (size_t)t * HID + p * 64)                              // fwd half
      : (hs + (size_t)(SEQ + (SEQ - 1 - t)) * HID + (p - 4) * 64);   // bwd half
  const float* __restrict__ wt = w_tag + (size_t)j * (2 * HID) + p * 64;
  float sum = 0.f;
  #pragma unroll
  for (int k = 0; k < 64; k += 4) {
    const float4 x4 = *reinterpret_cast<const float4*>(&src[k]);
    const float4 w4 = *reinterpret_cast<const float4*>(&wt[k]);
    sum = fmaf(x4.x, w4.x, sum); sum = fmaf(x4.y, w4.y, sum);
    sum = fmaf(x4.z, w4.z, sum); sum = fmaf(x4.w, w4.w, sum);
  }
  sum += __shfl_down(sum, 4, 8);
  sum += __shfl_down(sum, 2, 8);
  sum += __shfl_down(sum, 1, 8);
  if (p == 0) feats[(size_t)t * NTAG + j] = sum + b_tag[j];
}

// ---------------------------------------------------------------------------
// Kernel 4: Viterbi + backtrace, single wave. Tie-breaking matches
// jnp.argmax (first index): strict '>' updates, lower half wins ties.
// ---------------------------------------------------------------------------
__global__ __launch_bounds__(64) void viterbi_kernel(
    const float* __restrict__ feats, const float* __restrict__ trans,
    float* __restrict__ out)
{
  __shared__ unsigned char bp[SEQ][NTAG];   // 64 KiB exactly
  const int lane = threadIdx.x;
  const int j = lane & 31, half = lane >> 5;
  float tr[16];
  #pragma unroll
  for (int qq = 0; qq < 16; ++qq) tr[qq] = trans[j * NTAG + half * 16 + qq];
  float fv = (j == 30) ? 0.0f : FNEG;       // START = 30
  float fcur = feats[j];
  for (int t = 0; t < SEQ; ++t) {
    const int tn = (t + 1 < SEQ) ? (t + 1) : (SEQ - 1);
    const float fnext = feats[(size_t)tn * NTAG + j];
    float best = -3.0e38f; int barg = 0;
    #pragma unroll
    for (int qq = 0; qq < 16; ++qq) {
      const int p = half * 16 + qq;
      const float sc = __shfl(fv, p) + tr[qq];
      if (sc > best) { best = sc; barg = p; }
    }
    const float ob = __shfl_down(best, 32);
    const int   oa = __shfl_down(barg, 32);
    float fvnew = 0.f;
    if (half == 0) {
      if (ob > best) { best = ob; barg = oa; }
      bp[t][j] = (unsigned char)barg;
      fvnew = best + fcur;
    }
    fv = __shfl(fvnew, j);   // broadcast updated fv[j] to both halves
    fcur = fnext;
  }
  float term = fv + trans[31 * NTAG + j];   // STOP = 31
  int idx = j;
  #pragma unroll
  for (int off = 16; off >= 1; off >>= 1) {
    const float ov = __shfl_down(term, off, 32);
    const int   oi = __shfl_down(idx, off, 32);
    if (ov > term) { term = ov; idx = oi; }
  }
  if (lane == 0) {
    out[0] = term;                 // path score
    int tag = idx;
    for (int t = SEQ - 1; t >= 0; --t) {
      out[1 + t] = (float)tag;     // y[S-1] = best_last; y[t] = bp[t+1][y[t+1]]
      tag = bp[t][tag];
    }
  }
}

// ---------------------------------------------------------------------------
extern "C" void kernel_launch(void* const* d_in, const int* in_sizes, int n_in,
                              void* d_out, int out_size, void* d_ws, size_t ws_size,
                              hipStream_t stream)
{
  (void)in_sizes; (void)n_in; (void)out_size; (void)ws_size;
  const int*   sent   = (const int*)  d_in[0];
  const float* embed  = (const float*)d_in[1];
  const float* w_ih_f = (const float*)d_in[2];
  const float* w_hh_f = (const float*)d_in[3];
  const float* b_f    = (const float*)d_in[4];
  const float* w_ih_b = (const float*)d_in[5];
  const float* w_hh_b = (const float*)d_in[6];
  const float* b_b    = (const float*)d_in[7];
  const float* w_tag  = (const float*)d_in[8];
  const float* b_tag  = (const float*)d_in[9];
  const float* trans  = (const float*)d_in[10];
  const float* h0     = (const float*)d_in[11];
  const float* c0     = (const float*)d_in[12];
  float* out = (float*)d_out;

  // ws: hx[2][S][256] u64 | px[2][S][1024] f32 | hs[2][S][256] | feats | ctl
  unsigned long long* hx = (unsigned long long*)d_ws;          // 8 MB
  float* px    = (float*)(hx + (size_t)2 * SEQ * HID);         // 16 MB
  float* hsbuf = px + (size_t)2 * SEQ * GATE;                  // 4 MB
  float* feats = hsbuf + (size_t)2 * SEQ * HID;                // 256 KB
  unsigned* ctl = (unsigned*)(feats + (size_t)SEQ * NTAG);     // 64 B

  init_ctl<<<1, 64, 0, stream>>>(ctl);
  dim3 gemm_grid(SEQ / 64, GATE / 64, 2);
  px_gemm<<<gemm_grid, 256, 0, stream>>>(sent, embed, w_ih_f, b_f,
                                         w_ih_b, b_b, px);
  lstm_xcd<<<NBLK, 256, 0, stream>>>(px, w_hh_f, w_hh_b, h0, c0,
                                     hsbuf, hx, ctl);
  feats_kernel<<<SEQ, 256, 0, stream>>>(hsbuf, w_tag, b_tag, feats);
  viterbi_kernel<<<1, 64, 0, stream>>>(feats, trans, out);
}